// Round 6
// baseline (410.129 us; speedup 1.0000x reference)
//
#include <hip/hip_runtime.h>
#include <stdint.h>

// VQ-VAE quantise round. N=16, W=512, T=1024, K=2048, NT=16384.
// Round 6: argmin LDS staged in MFMA-fragment order via per-lane global_load_lds
// gather -> ds_read_b128 is contiguous (zero bank conflicts; was 1.49e7 conflict
// cycles = ~22% of kernel). vq_hist fused into vq_bits.

#define W_   512
#define T_   1024
#define K_   2048
#define NT_  16384

#define RNG_VARIANT 0
#define XG_CAP 1536

typedef unsigned short ushort_t;
typedef __attribute__((ext_vector_type(8))) short short8;
typedef __attribute__((ext_vector_type(4))) float f32x4;

// ---- workspace layout (bytes) ----
#define OFF_XHI     0u          // bf16 hi of xf [NT][512]   16 MB
#define OFF_XLO     16777216u   // bf16 lo                   16 MB
#define OFF_KHI     33554432u   // bf16 hi of k [K][512]      2 MB
#define OFF_KLO     35651584u   //                            2 MB
#define OFF_PM1     37748736u   // per-colblock min1 u64[16][NT]  2 MB
#define OFF_PM2     39845888u   // per-colblock min2 f32[16][NT]  1 MB
#define OFF_XG      37748736u   // fp32 gathered flagged rows (overlays PM1+PM2 after merge)
// rank scratch overlays PM2 region (dead until argmin writes pm2; rank runs first)
#define R_HIST      39845888u   // i32[2][4096]  32 KB  (zeroed)
#define R_CUR       39878656u   // i32[2][4096]  32 KB  (zeroed)
#define R_BASE      39911424u   // i32[2][4100]  ~33 KB
#define R_SLOT      39944448u   // i32[2][16384] 128 KB
#define OFF_PACKED  40894464u   // u64[NT] final (dist,idx)  128 KB
#define OFF_FLIST   41025536u   // i32[NT] compacted flagged rows  64 KB
#define OFF_X2      41091072u   // f32[NT]                    64 KB
#define OFF_K2      41156608u   // f32[K]                      8 KB
#define OFF_SCAL    41164800u   // [0]=sum [1]=sumsq [2]=fit [3]=dk2; int[8]=nflag (zero)
#define OFF_COUNTS  41165056u   // f32[K]   (zero)
#define OFF_CURSOR  41173248u   // i32[K]   (zero)
#define OFF_RANK1   41181440u   // (zero)
#define OFF_RANK2   41246976u   // (zero)
#define ZERO_LEN    147712u     // SCAL..RANK2 end
#define OFF_BITS1   41312512u
#define OFF_BITS2   41378048u
#define OFF_OFFS    41443584u   // i32[2049]
#define OFF_ROWL    41452032u   // i32[NT]
#define OFF_KRAND   41517568u   // i32[K]

// out offsets (floats)
#define O_XL    0u
#define O_XD    16384u
#define O_SC    8404992u
#define O_KNEW  8404997u
#define O_KSN   9453573u
#define O_KEN   10502149u

__device__ __forceinline__ float bf2f(ushort_t u) {
  return __uint_as_float(((unsigned)u) << 16);
}
__device__ __forceinline__ ushort_t f2bf(float v) {
  unsigned u = __float_as_uint(v);
  unsigned r = u + 0x7FFFu + ((u >> 16) & 1u);
  return (ushort_t)(r >> 16);
}
__device__ __forceinline__ void gload_lds16(const void* g, void* l) {
  __builtin_amdgcn_global_load_lds(
      (const __attribute__((address_space(1))) unsigned*)g,
      (__attribute__((address_space(3))) unsigned*)l, 16, 0, 0);
}

// ---------------- threefry2x32 (jax key schedule) ----------------
__device__ __forceinline__ void tf2x32(uint32_t k0, uint32_t k1,
                                       uint32_t x0, uint32_t x1,
                                       uint32_t& o0, uint32_t& o1) {
  const uint32_t ks2 = k0 ^ k1 ^ 0x1BD11BDAu;
  x0 += k0; x1 += k1;
#define ROUND4(a,b,c,d) \
  x0+=x1; x1=(x1<<(a))|(x1>>(32-(a))); x1^=x0; \
  x0+=x1; x1=(x1<<(b))|(x1>>(32-(b))); x1^=x0; \
  x0+=x1; x1=(x1<<(c))|(x1>>(32-(c))); x1^=x0; \
  x0+=x1; x1=(x1<<(d))|(x1>>(32-(d))); x1^=x0;
  ROUND4(13,15,26,6)  x0+=k1;  x1+=ks2+1u;
  ROUND4(17,29,16,24) x0+=ks2; x1+=k0+2u;
  ROUND4(13,15,26,6)  x0+=k0;  x1+=k1+3u;
  ROUND4(17,29,16,24) x0+=k1;  x1+=ks2+4u;
  ROUND4(13,15,26,6)  x0+=ks2; x1+=k0+5u;
#undef ROUND4
  o0 = x0; o1 = x1;
}

// ---------------- prep x: transpose -> xhi/xlo bf16, x2, global sums ----------------
__global__ void vq_prep_x(const float* __restrict__ x, ushort_t* __restrict__ xhi,
                          ushort_t* __restrict__ xlo, float* __restrict__ x2,
                          float* __restrict__ scal) {
  __shared__ float tile[64][65];
  __shared__ float x2s[64];
  __shared__ float rs[4], rq[4];
  int b = blockIdx.x;
  int n = b >> 4, tc = b & 15;
  int t0 = tc * 64;
  int tid = threadIdx.x;
  if (tid < 64) x2s[tid] = 0.f;
  __syncthreads();
  float gs = 0.f, gq = 0.f;
  const size_t xb = (size_t)n * (W_ * T_);
  int tl = tid & 63, wg = tid >> 6;
  int wl = 2 * (tid & 31), tg = tid >> 5;
  for (int p = 0; p < 8; p++) {
    int w0 = p * 64;
#pragma unroll 4
    for (int s = 0; s < 16; s++) {
      int w = s * 4 + wg;
      tile[tl][w] = x[xb + (size_t)(w0 + w) * T_ + t0 + tl];
    }
    __syncthreads();
#pragma unroll
    for (int s = 0; s < 8; s++) {
      int t = s * 8 + tg;
      float v0 = tile[t][wl], v1 = tile[t][wl + 1];
      ushort_t h0 = f2bf(v0); ushort_t l0 = f2bf(v0 - bf2f(h0));
      ushort_t h1 = f2bf(v1); ushort_t l1 = f2bf(v1 - bf2f(h1));
      size_t row = (size_t)n * 1024 + t0 + t;
      ushort2 hv; hv.x = h0; hv.y = h1;
      ushort2 lv; lv.x = l0; lv.y = l1;
      *(ushort2*)&xhi[row * 512 + w0 + wl] = hv;
      *(ushort2*)&xlo[row * 512 + w0 + wl] = lv;
      gs += v0 + v1;
      float part = v0 * v0 + v1 * v1;
      gq += part;
      for (int off = 16; off; off >>= 1) part += __shfl_down(part, off, 32);
      if ((tid & 31) == 0) x2s[t] += part;
    }
    __syncthreads();
  }
  for (int off = 32; off; off >>= 1) { gs += __shfl_down(gs, off, 64); gq += __shfl_down(gq, off, 64); }
  if ((tid & 63) == 0) { rs[tid >> 6] = gs; rq[tid >> 6] = gq; }
  __syncthreads();
  if (tid == 0) {
    atomicAdd(&scal[0], rs[0] + rs[1] + rs[2] + rs[3]);
    atomicAdd(&scal[1], rq[0] + rq[1] + rq[2] + rq[3]);
  }
  if (tid < 64) x2[n * 1024 + t0 + tid] = x2s[tid];
}

// ---------------- prep k: khi/klo bf16 + k2 ----------------
__global__ void vq_prep_k(const float* __restrict__ k, ushort_t* __restrict__ khi,
                          ushort_t* __restrict__ klo, float* __restrict__ k2v) {
  int tid = threadIdx.x;
  int row = blockIdx.x * 8 + (tid >> 5);
  int wl = tid & 31;
  const float* kr = k + (size_t)row * 512;
  float acc = 0.f;
#pragma unroll
  for (int c = 0; c < 4; c++) {
    int w = c * 128 + wl * 4;
    float4 v = *(const float4*)(kr + w);
    ushort4 hv, lv;
    hv.x = f2bf(v.x); lv.x = f2bf(v.x - bf2f(hv.x));
    hv.y = f2bf(v.y); lv.y = f2bf(v.y - bf2f(hv.y));
    hv.z = f2bf(v.z); lv.z = f2bf(v.z - bf2f(hv.z));
    hv.w = f2bf(v.w); lv.w = f2bf(v.w - bf2f(hv.w));
    *(ushort4*)&khi[(size_t)row * 512 + w] = hv;
    *(ushort4*)&klo[(size_t)row * 512 + w] = lv;
    acc += v.x * v.x + v.y * v.y + v.z * v.z + v.w * v.w;
  }
  for (int off = 16; off; off >>= 1) acc += __shfl_down(acc, off, 32);
  if (wl == 0) k2v[row] = acc;
}

// ---------------- sort keys for both shuffle rounds + fused histogram ----------------
__global__ void vq_bits(uint32_t* __restrict__ bits1, uint32_t* __restrict__ bits2,
                        int* __restrict__ hist) {
  uint32_t i = blockIdx.x * 256 + threadIdx.x;
  uint32_t o0, o1;
  uint32_t v1, v2;
#if RNG_VARIANT == 2
  uint32_t a0, a1, b0, b1, c0, c1, d0, d1;
  tf2x32(0u, 42u, 0u, 2u, a0, a1);
  tf2x32(0u, 42u, 1u, 3u, b0, b1);
  uint32_t keyA0 = a0, keyA1 = b0, s1k0 = a1, s1k1 = b1;
  tf2x32(keyA0, keyA1, 0u, 2u, c0, c1);
  tf2x32(keyA0, keyA1, 1u, 3u, d0, d1);
  uint32_t s2k0 = c1, s2k1 = d1;
  uint32_t lo = (i < 8192u) ? i : (i - 8192u);
  tf2x32(s1k0, s1k1, lo, lo + 8192u, o0, o1);
  v1 = (i < 8192u) ? o0 : o1;
  tf2x32(s2k0, s2k1, lo, lo + 8192u, o0, o1);
  v2 = (i < 8192u) ? o0 : o1;
#else
  uint32_t a0, a1, b0, b1, c0, c1, d0, d1;
  tf2x32(0u, 42u, 0u, 0u, a0, a1);
  tf2x32(0u, 42u, 0u, 1u, b0, b1);
  tf2x32(a0, a1, 0u, 0u, c0, c1);
  tf2x32(a0, a1, 0u, 1u, d0, d1);
  (void)c0; (void)c1;
  tf2x32(b0, b1, 0u, i, o0, o1);
#if RNG_VARIANT == 0
  v1 = o1;
#else
  v1 = o0;
#endif
  tf2x32(d0, d1, 0u, i, o0, o1);
#if RNG_VARIANT == 0
  v2 = o1;
#else
  v2 = o0;
#endif
#endif
  bits1[i] = v1;
  bits2[i] = v2;
  atomicAdd(&hist[v1 >> 20], 1);
  atomicAdd(&hist[4096 + (v2 >> 20)], 1);
}

__global__ void vq_hscan(const int* __restrict__ hist, int* __restrict__ base) {
  int s = blockIdx.x;           // sort 0/1
  int t = threadIdx.x;
  __shared__ int wsum[4];
  int p = 0;
  int loc[16];
#pragma unroll
  for (int c = 0; c < 16; c++) { loc[c] = hist[s * 4096 + t * 16 + c]; p += loc[c]; }
  int orig = p;
  int lane = t & 63, wave = t >> 6;
#pragma unroll
  for (int off = 1; off < 64; off <<= 1) {
    int v = __shfl_up(p, off, 64);
    if (lane >= off) p += v;
  }
  if (lane == 63) wsum[wave] = p;
  __syncthreads();
  int add = 0;
  for (int w = 0; w < 4; w++) if (w < wave) add += wsum[w];
  int excl = p + add - orig;
#pragma unroll
  for (int c = 0; c < 16; c++) {
    base[s * 4100 + t * 16 + c] = excl;
    excl += loc[c];
  }
  if (t == 255) base[s * 4100 + 4096] = excl;
}

__global__ void vq_scatter(const uint32_t* __restrict__ bits1, const uint32_t* __restrict__ bits2,
                           const int* __restrict__ base, int* __restrict__ cur,
                           int* __restrict__ slot) {
  int i = blockIdx.x * 256 + threadIdx.x;
  {
    int b = bits1[i] >> 20;
    int pos = atomicAdd(&cur[b], 1);
    slot[base[b] + pos] = i;
  }
  {
    int b = bits2[i] >> 20;
    int pos = atomicAdd(&cur[4096 + b], 1);
    slot[16384 + base[4100 + b] + pos] = i;
  }
}

__global__ void vq_rank2(const uint32_t* __restrict__ bits1, const uint32_t* __restrict__ bits2,
                         const int* __restrict__ base, const int* __restrict__ slot,
                         uint32_t* __restrict__ rank1, uint32_t* __restrict__ rank2) {
  int g = blockIdx.x * 256 + threadIdx.x;
  int s = g >> 14, i = g & 16383;
  const uint32_t* bits = s ? bits2 : bits1;
  uint32_t ki = bits[i];
  int b = ki >> 20;
  int lo = base[s * 4100 + b], hi = base[s * 4100 + b + 1];
  int cnt = lo;
  for (int e = lo; e < hi; e++) {
    int j = slot[s * 16384 + e];
    uint32_t kj = bits[j];
    cnt += (kj < ki) || (kj == ki && j < i);
  }
  if (s) rank2[i] = (uint32_t)cnt; else rank1[i] = (uint32_t)cnt;
}

__global__ void vq_krand(const uint32_t* __restrict__ rank1, const uint32_t* __restrict__ rank2,
                         int* __restrict__ krand) {
  int i = blockIdx.x * 256 + threadIdx.x;
  uint32_t j = rank1[i] & 16383u;
  uint32_t p = rank2[j];
  if (p < K_) krand[p] = i;
}

// ---------------- MFMA argmin: 128x128 tile, BK=64, split-bf16 3-term ----------------
// LDS staged in MFMA-fragment order: chunk cid = (((g2*4+i)*2+kk)*4+quad)*16+lr,
// so each ds_read_b128 is base+lane*16 contiguous (conflict-free).
__global__ __launch_bounds__(256, 2) void vq_argmin_mfma(
    const ushort_t* __restrict__ xhi, const ushort_t* __restrict__ xlo,
    const ushort_t* __restrict__ khi, const ushort_t* __restrict__ klo,
    const float* __restrict__ x2, const float* __restrict__ k2,
    unsigned long long* __restrict__ pm1, float* __restrict__ pm2) {
  __shared__ __align__(16) char smem[65536];
  int tid = threadIdx.x;
  int bx = blockIdx.x & 127, by = blockIdx.x >> 7;
  int row0 = bx * 128, col0 = by * 128;
  int lane = tid & 63, wid = tid >> 6;
  int wm = wid >> 1, wn = wid & 1;
  int lr = lane & 15, quad = lane >> 4;

  const char* gb[4];
  gb[0] = (const char*)xhi + (size_t)row0 * 1024;
  gb[1] = (const char*)xlo + (size_t)row0 * 1024;
  gb[2] = (const char*)khi + (size_t)col0 * 1024;
  gb[3] = (const char*)klo + (size_t)col0 * 1024;
  uint32_t goff[4], loff[4];
#pragma unroll
  for (int it = 0; it < 4; it++) {
    int cid = it * 256 + tid;
    int lr5 = cid & 15;
    int quad5 = (cid >> 4) & 3;
    int kk5 = (cid >> 6) & 1;
    int i5 = (cid >> 7) & 3;
    int g25 = (cid >> 9) & 1;
    int grow = g25 * 64 + i5 * 16 + lr5;
    goff[it] = (uint32_t)(grow * 1024 + kk5 * 64 + quad5 * 16);
    loff[it] = (uint32_t)(cid * 16);
  }
  const int abase = wm * 8192 + lane * 16;
  const int bbase = wn * 8192 + lane * 16;
  f32x4 acc[4][4] = {};

  for (int kt = 0; kt < 8; kt++) {
    uint32_t kofs = (uint32_t)kt * 128;
#pragma unroll
    for (int tl = 0; tl < 4; tl++)
#pragma unroll
      for (int it = 0; it < 4; it++)
        gload_lds16(gb[tl] + goff[it] + kofs, &smem[tl * 16384 + loff[it]]);
    __syncthreads();
#pragma unroll
    for (int kk = 0; kk < 2; kk++) {
      short8 ah[4], al[4], bh[4], bl[4];
#pragma unroll
      for (int i = 0; i < 4; i++) {
        int ao = abase + (i * 2 + kk) * 1024;
        int bo = bbase + (i * 2 + kk) * 1024;
        ah[i] = *(const short8*)&smem[ao];
        al[i] = *(const short8*)&smem[16384 + ao];
        bh[i] = *(const short8*)&smem[32768 + bo];
        bl[i] = *(const short8*)&smem[49152 + bo];
      }
#pragma unroll
      for (int i = 0; i < 4; i++)
#pragma unroll
        for (int j = 0; j < 4; j++) {
          acc[i][j] = __builtin_amdgcn_mfma_f32_16x16x32_bf16(ah[i], bh[j], acc[i][j], 0, 0, 0);
          acc[i][j] = __builtin_amdgcn_mfma_f32_16x16x32_bf16(ah[i], bl[j], acc[i][j], 0, 0, 0);
          acc[i][j] = __builtin_amdgcn_mfma_f32_16x16x32_bf16(al[i], bh[j], acc[i][j], 0, 0, 0);
        }
    }
    __syncthreads();
  }

  // epilogue: per-row top-2 into LDS, then 32-slot merge
  unsigned long long* L1 = (unsigned long long*)smem;   // [128][32]
  float* L2f = (float*)&smem[32768];                    // [128][32]
  float k2c[4];
#pragma unroll
  for (int j = 0; j < 4; j++) k2c[j] = k2[col0 + wn * 64 + j * 16 + lr];
#pragma unroll
  for (int i = 0; i < 4; i++) {
#pragma unroll
    for (int r = 0; r < 4; r++) {
      int row_l = wm * 64 + i * 16 + quad * 4 + r;
      float x2r = x2[row0 + row_l];
      float m1 = 3.4e38f, m2 = 3.4e38f; int mi = 0;
#pragma unroll
      for (int j = 0; j < 4; j++) {
        float d = (x2r - 2.0f * acc[i][j][r]) + k2c[j];
        int kg = col0 + wn * 64 + j * 16 + lr;
        if (d < m1) { m2 = m1; m1 = d; mi = kg; } else m2 = fminf(m2, d);
      }
      L1[row_l * 32 + wn * 16 + lr] =
          (((unsigned long long)__float_as_uint(m1)) << 32) | (unsigned)mi;
      L2f[row_l * 32 + wn * 16 + lr] = m2;
    }
  }
  __syncthreads();
  if (tid < 128) {
    unsigned long long b1 = L1[tid * 32];
    float b2 = L2f[tid * 32];
    for (int c = 1; c < 32; c++) {
      unsigned long long v = L1[tid * 32 + c];
      float vf = L2f[tid * 32 + c];
      if (v < b1) { b2 = fminf(b2, __uint_as_float((unsigned)(b1 >> 32))); b1 = v; }
      else b2 = fminf(b2, __uint_as_float((unsigned)(v >> 32)));
      b2 = fminf(b2, vf);
    }
    pm1[(size_t)by * NT_ + row0 + tid] = b1;
    pm2[(size_t)by * NT_ + row0 + tid] = b2;
  }
}

// ---------------- merge 16 col-blocks -> packed + compacted near-tie list ----------------
__global__ void vq_merge(const unsigned long long* __restrict__ pm1,
                         const float* __restrict__ pm2,
                         unsigned long long* __restrict__ packed,
                         int* __restrict__ flist, int* __restrict__ nflag) {
  int r = blockIdx.x * 256 + threadIdx.x;
  unsigned long long b1 = pm1[r];
  float b2 = pm2[r];
  for (int c = 1; c < 16; c++) {
    unsigned long long v = pm1[(size_t)c * NT_ + r];
    float vf = pm2[(size_t)c * NT_ + r];
    if (v < b1) { b2 = fminf(b2, __uint_as_float((unsigned)(b1 >> 32))); b1 = v; }
    else b2 = fminf(b2, __uint_as_float((unsigned)(v >> 32)));
    b2 = fminf(b2, vf);
  }
  if ((b2 - __uint_as_float((unsigned)(b1 >> 32))) < 3e-4f) {
    packed[r] = 0xFFFFFFFFFFFFFFFFull;
    int pos = atomicAdd(nflag, 1);
    flist[pos] = r;
  } else {
    packed[r] = b1;
  }
}

// ---------------- gather flagged x rows to dense fp32 (coalesced writes) ----------------
__global__ void vq_gatherx(const float* __restrict__ x, const int* __restrict__ flist,
                           const int* __restrict__ nflag, float* __restrict__ xg) {
  int nf = *nflag; if (nf > XG_CAP) nf = XG_CAP;
  int total = nf * 512;
  for (int e = blockIdx.x * 256 + threadIdx.x; e < total; e += gridDim.x * 256) {
    int ii = e >> 9, c = e & 511;
    int r = flist[ii];
    xg[e] = x[(size_t)(r >> 10) * 524288 + (size_t)c * 1024 + (r & 1023)];
  }
}

// ---------------- fp32 exact repair: (8-row group) x (256-cluster chunk) ----------------
__global__ void vq_repair(const float* __restrict__ x, const float* __restrict__ k,
                          const float* __restrict__ xg,
                          const float* __restrict__ x2, const float* __restrict__ k2,
                          const int* __restrict__ flist, const int* __restrict__ nflag,
                          unsigned long long* __restrict__ packed) {
  __shared__ float xs[8][512];
  __shared__ unsigned long long part[8][4];
  int tid = threadIdx.x;
  int lane = tid & 63, wave = tid >> 6;
  int nf = *nflag;
  int ngrp = (nf + 7) >> 3;
  int nwork = ngrp * 8;
  for (int wi = blockIdx.x; wi < nwork; wi += gridDim.x) {
    int g = wi >> 3, c = wi & 7;
    int base = g * 8;
    for (int e = tid; e < 8 * 512; e += 256) {
      int rr = e >> 9, cc = e & 511;
      int ii = base + rr;
      float v = 0.f;
      if (ii < nf) {
        if (ii < XG_CAP) v = xg[ii * 512 + cc];
        else { int r = flist[ii]; v = x[(size_t)(r >> 10) * 524288 + (size_t)cc * 1024 + (r & 1023)]; }
      }
      xs[rr][cc] = v;
    }
    __syncthreads();
    int j = c * 256 + tid;
    const float4* kr = (const float4*)(k + (size_t)j * 512);
    float dot[8] = {0.f, 0.f, 0.f, 0.f, 0.f, 0.f, 0.f, 0.f};
    for (int w4 = 0; w4 < 128; w4++) {
      float4 kv = kr[w4];
#pragma unroll
      for (int rr = 0; rr < 8; rr++) {
        const float4 xv = *(const float4*)&xs[rr][w4 * 4];
        dot[rr] = fmaf(xv.x, kv.x, dot[rr]);
        dot[rr] = fmaf(xv.y, kv.y, dot[rr]);
        dot[rr] = fmaf(xv.z, kv.z, dot[rr]);
        dot[rr] = fmaf(xv.w, kv.w, dot[rr]);
      }
    }
    float k2j = k2[j];
#pragma unroll
    for (int rr = 0; rr < 8; rr++) {
      int ii = base + rr;
      unsigned long long pv = 0xFFFFFFFFFFFFFFFFull;
      if (ii < nf) {
        int r = flist[ii];
        float d = (x2[r] - 2.0f * dot[rr]) + k2j;
        pv = (((unsigned long long)__float_as_uint(d)) << 32) | (unsigned)j;
      }
      for (int off = 32; off; off >>= 1) {
        unsigned long long o = __shfl_down(pv, off, 64);
        if (o < pv) pv = o;
      }
      if (lane == 0) part[rr][wave] = pv;
    }
    __syncthreads();
    if (tid < 8) {
      int ii = base + tid;
      if (ii < nf) {
        unsigned long long m = part[tid][0];
        if (part[tid][1] < m) m = part[tid][1];
        if (part[tid][2] < m) m = part[tid][2];
        if (part[tid][3] < m) m = part[tid][3];
        atomicMin(&packed[flist[ii]], m);
      }
    }
    __syncthreads();
  }
}

// ---------------- x_l, counts, fit ----------------
__global__ void vq_cnt2(const unsigned long long* __restrict__ packed,
                        float* __restrict__ counts, float* __restrict__ scal,
                        float* __restrict__ out) {
  int tid = threadIdx.x;
  int r = blockIdx.x * 256 + tid;
  unsigned long long p = packed[r];
  unsigned idx = (unsigned)(p & 0xFFFFFFFFull);
  float md = __uint_as_float((unsigned)(p >> 32));
  out[O_XL + r] = (float)idx;
  atomicAdd(&counts[idx], 1.0f);
  float s = md;
  for (int off = 32; off; off >>= 1) s += __shfl_down(s, off, 64);
  __shared__ float rs[4];
  if ((tid & 63) == 0) rs[tid >> 6] = s;
  __syncthreads();
  if (tid == 0) atomicAdd(&scal[2], rs[0] + rs[1] + rs[2] + rs[3]);
}

// ---------------- exclusive scan of counts -> offsets ----------------
__global__ void vq_scan(const float* __restrict__ counts, int* __restrict__ offs) {
  __shared__ int ls[256];
  int t = threadIdx.x;
  int s = 0;
#pragma unroll
  for (int c = 0; c < 8; c++) s += (int)counts[t * 8 + c];
  ls[t] = s;
  __syncthreads();
  if (t == 0) {
    int run = 0;
    for (int i = 0; i < 256; i++) { int v = ls[i]; ls[i] = run; run += v; }
  }
  __syncthreads();
  int base = ls[t];
#pragma unroll
  for (int c = 0; c < 8; c++) {
    offs[t * 8 + c] = base;
    base += (int)counts[t * 8 + c];
  }
  if (t == 255) offs[2048] = base;
}

// ---------------- fill CSR row list ----------------
__global__ void vq_fill(const unsigned long long* __restrict__ packed,
                        const int* __restrict__ offs, int* __restrict__ cursor,
                        int* __restrict__ rowl) {
  int r = blockIdx.x * 256 + threadIdx.x;
  int idx = (int)(packed[r] & 0xFFFFFFFFull);
  int pos = atomicAdd(&cursor[idx], 1);
  rowl[offs[idx] + pos] = r;
}

// ---------------- x_d gather/store ----------------
__global__ void vq_xd(const float* __restrict__ k,
                      const unsigned long long* __restrict__ packed,
                      float* __restrict__ out) {
  __shared__ float kb[16][513];
  __shared__ int lrow[16];
  int rb = blockIdx.x;
  int row0 = rb * 16;
  int n = row0 >> 10, t0 = row0 & 1023;
  int tid = threadIdx.x;
  if (tid < 16) lrow[tid] = (int)(packed[row0 + tid] & 0xFFFFFFFFull);
  __syncthreads();
  for (int i = tid; i < 16 * 512; i += 256) {
    int rr = i >> 9, c = i & 511;
    kb[rr][c] = k[(size_t)lrow[rr] * 512 + c];
  }
  __syncthreads();
  int tp = tid & 15, wp = tid >> 4;
  float* xd = out + O_XD;
  int t = t0 + tp;
#pragma unroll 4
  for (int wi = 0; wi < 32; wi++) {
    int w = wi * 16 + wp;
    xd[(size_t)n * 524288 + (size_t)w * 1024 + t] = kb[tp][w];
  }
}

// ---------------- codebook EMA update via CSR gather ----------------
__global__ void vq_knew_csr(const ushort_t* __restrict__ xhi, const ushort_t* __restrict__ xlo,
                            const float* __restrict__ k, const float* __restrict__ ksum_in,
                            const float* __restrict__ kelem_in, const int* __restrict__ offs,
                            const int* __restrict__ rowl, const int* __restrict__ krand,
                            float* __restrict__ out, float* __restrict__ scal) {
  int j = blockIdx.x, tid = threadIdx.x;
  int o0 = offs[j], o1 = offs[j + 1];
  float s0 = 0.f, s1 = 0.f;
  for (int p = o0; p < o1; p++) {
    int r = rowl[p];
    const ushort_t* hp = &xhi[(size_t)r * 512];
    const ushort_t* lp = &xlo[(size_t)r * 512];
    s0 += bf2f(hp[tid]) + bf2f(lp[tid]);
    s1 += bf2f(hp[tid + 256]) + bf2f(lp[tid + 256]);
  }
  float cnt = (float)(o1 - o0);
  float ken = 0.99f * kelem_in[j] + 0.01f * cnt;
  bool use = (ken >= 1.0f);
  int ir = krand[j] & 16383;
  float dd = 0.f;
  {
    float ksn = 0.99f * ksum_in[(size_t)j * 512 + tid] + 0.01f * s0;
    out[O_KSN + (size_t)j * 512 + tid] = ksn;
    float kn = use ? (ksn / ken)
                   : (bf2f(xhi[(size_t)ir * 512 + tid]) + bf2f(xlo[(size_t)ir * 512 + tid]));
    out[O_KNEW + (size_t)j * 512 + tid] = kn;
    float d = kn - k[(size_t)j * 512 + tid];
    dd += d * d;
  }
  {
    int w = tid + 256;
    float ksn = 0.99f * ksum_in[(size_t)j * 512 + w] + 0.01f * s1;
    out[O_KSN + (size_t)j * 512 + w] = ksn;
    float kn = use ? (ksn / ken)
                   : (bf2f(xhi[(size_t)ir * 512 + w]) + bf2f(xlo[(size_t)ir * 512 + w]));
    out[O_KNEW + (size_t)j * 512 + w] = kn;
    float d = kn - k[(size_t)j * 512 + w];
    dd += d * d;
  }
  for (int off = 32; off; off >>= 1) dd += __shfl_down(dd, off, 64);
  __shared__ float r4[4];
  if ((tid & 63) == 0) r4[tid >> 6] = dd;
  __syncthreads();
  if (tid == 0) {
    atomicAdd(&scal[3], r4[0] + r4[1] + r4[2] + r4[3]);
    out[O_KEN + j] = ken;
  }
}

// ---------------- scalars ----------------
__global__ void vq_fin(const float* __restrict__ counts, const float* __restrict__ scal,
                       float* __restrict__ out) {
  int tid = threadIdx.x;
  float e = 0.f;
  for (int j = tid; j < K_; j += 256) {
    float p = counts[j] * (1.0f / 16384.0f);
    e -= p * logf(p + 1e-8f);
  }
  for (int off = 32; off; off >>= 1) e += __shfl_down(e, off, 64);
  __shared__ float r[4];
  if ((tid & 63) == 0) r[tid >> 6] = e;
  __syncthreads();
  if (tid == 0) {
    float ent = r[0] + r[1] + r[2] + r[3];
    float sum = scal[0], sumsq = scal[1], fits = scal[2], d2 = scal[3];
    const float S = 8388608.f;
    out[O_SC + 0] = fits / S;
    out[O_SC + 1] = fits / 16384.f;
    out[O_SC + 2] = sqrtf((sumsq - sum * sum / S) / S);
    out[O_SC + 3] = ent;
    out[O_SC + 4] = sqrtf(d2 / 1048576.f);
  }
}

extern "C" void kernel_launch(void* const* d_in, const int* in_sizes, int n_in,
                              void* d_out, int out_size, void* d_ws, size_t ws_size,
                              hipStream_t stream) {
  (void)in_sizes; (void)n_in; (void)out_size; (void)ws_size;
  const float* x        = (const float*)d_in[0];
  const float* k        = (const float*)d_in[1];
  const float* ksum_in  = (const float*)d_in[2];
  const float* kelem_in = (const float*)d_in[3];
  float* out = (float*)d_out;
  uint8_t* ws = (uint8_t*)d_ws;

  ushort_t* xhi = (ushort_t*)(ws + OFF_XHI);
  ushort_t* xlo = (ushort_t*)(ws + OFF_XLO);
  ushort_t* khi = (ushort_t*)(ws + OFF_KHI);
  ushort_t* klo = (ushort_t*)(ws + OFF_KLO);
  unsigned long long* pm1 = (unsigned long long*)(ws + OFF_PM1);
  float*    pm2    = (float*)(ws + OFF_PM2);
  float*    xg     = (float*)(ws + OFF_XG);
  int*      rhist  = (int*)(ws + R_HIST);
  int*      rcur   = (int*)(ws + R_CUR);
  int*      rbase  = (int*)(ws + R_BASE);
  int*      rslot  = (int*)(ws + R_SLOT);
  unsigned long long* packed = (unsigned long long*)(ws + OFF_PACKED);
  int*      flist  = (int*)(ws + OFF_FLIST);
  float*    x2v    = (float*)(ws + OFF_X2);
  float*    k2v    = (float*)(ws + OFF_K2);
  float*    scal   = (float*)(ws + OFF_SCAL);
  int*      nflag  = (int*)(ws + OFF_SCAL + 32);
  float*    counts = (float*)(ws + OFF_COUNTS);
  int*      cursor = (int*)(ws + OFF_CURSOR);
  uint32_t* rank1  = (uint32_t*)(ws + OFF_RANK1);
  uint32_t* rank2  = (uint32_t*)(ws + OFF_RANK2);
  uint32_t* bits1  = (uint32_t*)(ws + OFF_BITS1);
  uint32_t* bits2  = (uint32_t*)(ws + OFF_BITS2);
  int*      offs   = (int*)(ws + OFF_OFFS);
  int*      rowl   = (int*)(ws + OFF_ROWL);
  int*      krand  = (int*)(ws + OFF_KRAND);

  hipMemsetAsync(ws + OFF_SCAL, 0, ZERO_LEN, stream);
  hipMemsetAsync(ws + R_HIST, 0, 65536, stream);   // hist + cursor

  vq_prep_x<<<256, 256, 0, stream>>>(x, xhi, xlo, x2v, scal);
  vq_prep_k<<<256, 256, 0, stream>>>(k, khi, klo, k2v);
  vq_bits<<<64, 256, 0, stream>>>(bits1, bits2, rhist);
  vq_hscan<<<2, 256, 0, stream>>>(rhist, rbase);
  vq_scatter<<<64, 256, 0, stream>>>(bits1, bits2, rbase, rcur, rslot);
  vq_rank2<<<128, 256, 0, stream>>>(bits1, bits2, rbase, rslot, rank1, rank2);
  vq_krand<<<64, 256, 0, stream>>>(rank1, rank2, krand);
  vq_argmin_mfma<<<2048, 256, 0, stream>>>(xhi, xlo, khi, klo, x2v, k2v, pm1, pm2);
  vq_merge<<<64, 256, 0, stream>>>(pm1, pm2, packed, flist, nflag);
  vq_gatherx<<<256, 256, 0, stream>>>(x, flist, nflag, xg);
  vq_repair<<<512, 256, 0, stream>>>(x, k, xg, x2v, k2v, flist, nflag, packed);
  vq_cnt2<<<64, 256, 0, stream>>>(packed, counts, scal, out);
  vq_scan<<<1, 256, 0, stream>>>(counts, offs);
  vq_fill<<<64, 256, 0, stream>>>(packed, offs, cursor, rowl);
  vq_xd<<<1024, 256, 0, stream>>>(k, packed, out);
  vq_knew_csr<<<2048, 256, 0, stream>>>(xhi, xlo, k, ksum_in, kelem_in, offs, rowl, krand, out, scal);
  vq_fin<<<1, 256, 0, stream>>>(counts, scal, out);
}

// Round 7
// 340.102 us; speedup vs baseline: 1.2059x; 1.2059x over previous
//
#include <hip/hip_runtime.h>
#include <stdint.h>

// VQ-VAE quantise round. N=16, W=512, T=1024, K=2048, NT=16384.
// Round 7: REVERT round-6 fragment-order staging (destroyed global coalescing;
// MfmaUtil 42->24). Real conflict source was the epilogue [128][32] u64 arrays
// (stride 256B -> all 64 lanes same bank pair, 1.486e7 cycles both rounds).
// Fix: pad epilogue to [128][33]. K-loop = round-5 layout (coalesced + XOR swizzle).

#define W_   512
#define T_   1024
#define K_   2048
#define NT_  16384

#define RNG_VARIANT 0
#define XG_CAP 1536

typedef unsigned short ushort_t;
typedef __attribute__((ext_vector_type(8))) short short8;
typedef __attribute__((ext_vector_type(4))) float f32x4;

// ---- workspace layout (bytes) ----
#define OFF_XHI     0u          // bf16 hi of xf [NT][512]   16 MB
#define OFF_XLO     16777216u   // bf16 lo                   16 MB
#define OFF_KHI     33554432u   // bf16 hi of k [K][512]      2 MB
#define OFF_KLO     35651584u   //                            2 MB
#define OFF_PM1     37748736u   // per-colblock min1 u64[16][NT]  2 MB
#define OFF_PM2     39845888u   // per-colblock min2 f32[16][NT]  1 MB
#define OFF_XG      37748736u   // fp32 gathered flagged rows (overlays PM1+PM2 after merge)
// rank scratch overlays PM2 region (dead until argmin writes pm2; rank runs first)
#define R_HIST      39845888u   // i32[2][4096]  32 KB  (zeroed)
#define R_CUR       39878656u   // i32[2][4096]  32 KB  (zeroed)
#define R_BASE      39911424u   // i32[2][4100]  ~33 KB
#define R_SLOT      39944448u   // i32[2][16384] 128 KB
#define OFF_PACKED  40894464u   // u64[NT] final (dist,idx)  128 KB
#define OFF_FLIST   41025536u   // i32[NT] compacted flagged rows  64 KB
#define OFF_X2      41091072u   // f32[NT]                    64 KB
#define OFF_K2      41156608u   // f32[K]                      8 KB
#define OFF_SCAL    41164800u   // [0]=sum [1]=sumsq [2]=fit [3]=dk2; int[8]=nflag (zero)
#define OFF_COUNTS  41165056u   // f32[K]   (zero)
#define OFF_CURSOR  41173248u   // i32[K]   (zero)
#define OFF_RANK1   41181440u   // (zero)
#define OFF_RANK2   41246976u   // (zero)
#define ZERO_LEN    147712u     // SCAL..RANK2 end
#define OFF_BITS1   41312512u
#define OFF_BITS2   41378048u
#define OFF_OFFS    41443584u   // i32[2049]
#define OFF_ROWL    41452032u   // i32[NT]
#define OFF_KRAND   41517568u   // i32[K]

// out offsets (floats)
#define O_XL    0u
#define O_XD    16384u
#define O_SC    8404992u
#define O_KNEW  8404997u
#define O_KSN   9453573u
#define O_KEN   10502149u

__device__ __forceinline__ float bf2f(ushort_t u) {
  return __uint_as_float(((unsigned)u) << 16);
}
__device__ __forceinline__ ushort_t f2bf(float v) {
  unsigned u = __float_as_uint(v);
  unsigned r = u + 0x7FFFu + ((u >> 16) & 1u);
  return (ushort_t)(r >> 16);
}
__device__ __forceinline__ void gload_lds16(const void* g, void* l) {
  __builtin_amdgcn_global_load_lds(
      (const __attribute__((address_space(1))) unsigned*)g,
      (__attribute__((address_space(3))) unsigned*)l, 16, 0, 0);
}

// ---------------- threefry2x32 (jax key schedule) ----------------
__device__ __forceinline__ void tf2x32(uint32_t k0, uint32_t k1,
                                       uint32_t x0, uint32_t x1,
                                       uint32_t& o0, uint32_t& o1) {
  const uint32_t ks2 = k0 ^ k1 ^ 0x1BD11BDAu;
  x0 += k0; x1 += k1;
#define ROUND4(a,b,c,d) \
  x0+=x1; x1=(x1<<(a))|(x1>>(32-(a))); x1^=x0; \
  x0+=x1; x1=(x1<<(b))|(x1>>(32-(b))); x1^=x0; \
  x0+=x1; x1=(x1<<(c))|(x1>>(32-(c))); x1^=x0; \
  x0+=x1; x1=(x1<<(d))|(x1>>(32-(d))); x1^=x0;
  ROUND4(13,15,26,6)  x0+=k1;  x1+=ks2+1u;
  ROUND4(17,29,16,24) x0+=ks2; x1+=k0+2u;
  ROUND4(13,15,26,6)  x0+=k0;  x1+=k1+3u;
  ROUND4(17,29,16,24) x0+=k1;  x1+=ks2+4u;
  ROUND4(13,15,26,6)  x0+=ks2; x1+=k0+5u;
#undef ROUND4
  o0 = x0; o1 = x1;
}

// ---------------- prep x: transpose -> xhi/xlo bf16, x2, global sums ----------------
__global__ void vq_prep_x(const float* __restrict__ x, ushort_t* __restrict__ xhi,
                          ushort_t* __restrict__ xlo, float* __restrict__ x2,
                          float* __restrict__ scal) {
  __shared__ float tile[64][65];
  __shared__ float x2s[64];
  __shared__ float rs[4], rq[4];
  int b = blockIdx.x;
  int n = b >> 4, tc = b & 15;
  int t0 = tc * 64;
  int tid = threadIdx.x;
  if (tid < 64) x2s[tid] = 0.f;
  __syncthreads();
  float gs = 0.f, gq = 0.f;
  const size_t xb = (size_t)n * (W_ * T_);
  int tl = tid & 63, wg = tid >> 6;
  int wl = 2 * (tid & 31), tg = tid >> 5;
  for (int p = 0; p < 8; p++) {
    int w0 = p * 64;
#pragma unroll 4
    for (int s = 0; s < 16; s++) {
      int w = s * 4 + wg;
      tile[tl][w] = x[xb + (size_t)(w0 + w) * T_ + t0 + tl];
    }
    __syncthreads();
#pragma unroll
    for (int s = 0; s < 8; s++) {
      int t = s * 8 + tg;
      float v0 = tile[t][wl], v1 = tile[t][wl + 1];
      ushort_t h0 = f2bf(v0); ushort_t l0 = f2bf(v0 - bf2f(h0));
      ushort_t h1 = f2bf(v1); ushort_t l1 = f2bf(v1 - bf2f(h1));
      size_t row = (size_t)n * 1024 + t0 + t;
      ushort2 hv; hv.x = h0; hv.y = h1;
      ushort2 lv; lv.x = l0; lv.y = l1;
      *(ushort2*)&xhi[row * 512 + w0 + wl] = hv;
      *(ushort2*)&xlo[row * 512 + w0 + wl] = lv;
      gs += v0 + v1;
      float part = v0 * v0 + v1 * v1;
      gq += part;
      for (int off = 16; off; off >>= 1) part += __shfl_down(part, off, 32);
      if ((tid & 31) == 0) x2s[t] += part;
    }
    __syncthreads();
  }
  for (int off = 32; off; off >>= 1) { gs += __shfl_down(gs, off, 64); gq += __shfl_down(gq, off, 64); }
  if ((tid & 63) == 0) { rs[tid >> 6] = gs; rq[tid >> 6] = gq; }
  __syncthreads();
  if (tid == 0) {
    atomicAdd(&scal[0], rs[0] + rs[1] + rs[2] + rs[3]);
    atomicAdd(&scal[1], rq[0] + rq[1] + rq[2] + rq[3]);
  }
  if (tid < 64) x2[n * 1024 + t0 + tid] = x2s[tid];
}

// ---------------- prep k: khi/klo bf16 + k2 ----------------
__global__ void vq_prep_k(const float* __restrict__ k, ushort_t* __restrict__ khi,
                          ushort_t* __restrict__ klo, float* __restrict__ k2v) {
  int tid = threadIdx.x;
  int row = blockIdx.x * 8 + (tid >> 5);
  int wl = tid & 31;
  const float* kr = k + (size_t)row * 512;
  float acc = 0.f;
#pragma unroll
  for (int c = 0; c < 4; c++) {
    int w = c * 128 + wl * 4;
    float4 v = *(const float4*)(kr + w);
    ushort4 hv, lv;
    hv.x = f2bf(v.x); lv.x = f2bf(v.x - bf2f(hv.x));
    hv.y = f2bf(v.y); lv.y = f2bf(v.y - bf2f(hv.y));
    hv.z = f2bf(v.z); lv.z = f2bf(v.z - bf2f(hv.z));
    hv.w = f2bf(v.w); lv.w = f2bf(v.w - bf2f(hv.w));
    *(ushort4*)&khi[(size_t)row * 512 + w] = hv;
    *(ushort4*)&klo[(size_t)row * 512 + w] = lv;
    acc += v.x * v.x + v.y * v.y + v.z * v.z + v.w * v.w;
  }
  for (int off = 16; off; off >>= 1) acc += __shfl_down(acc, off, 32);
  if (wl == 0) k2v[row] = acc;
}

// ---------------- sort keys for both shuffle rounds + fused histogram ----------------
__global__ void vq_bits(uint32_t* __restrict__ bits1, uint32_t* __restrict__ bits2,
                        int* __restrict__ hist) {
  uint32_t i = blockIdx.x * 256 + threadIdx.x;
  uint32_t o0, o1;
  uint32_t v1, v2;
#if RNG_VARIANT == 2
  uint32_t a0, a1, b0, b1, c0, c1, d0, d1;
  tf2x32(0u, 42u, 0u, 2u, a0, a1);
  tf2x32(0u, 42u, 1u, 3u, b0, b1);
  uint32_t keyA0 = a0, keyA1 = b0, s1k0 = a1, s1k1 = b1;
  tf2x32(keyA0, keyA1, 0u, 2u, c0, c1);
  tf2x32(keyA0, keyA1, 1u, 3u, d0, d1);
  uint32_t s2k0 = c1, s2k1 = d1;
  uint32_t lo = (i < 8192u) ? i : (i - 8192u);
  tf2x32(s1k0, s1k1, lo, lo + 8192u, o0, o1);
  v1 = (i < 8192u) ? o0 : o1;
  tf2x32(s2k0, s2k1, lo, lo + 8192u, o0, o1);
  v2 = (i < 8192u) ? o0 : o1;
#else
  uint32_t a0, a1, b0, b1, c0, c1, d0, d1;
  tf2x32(0u, 42u, 0u, 0u, a0, a1);
  tf2x32(0u, 42u, 0u, 1u, b0, b1);
  tf2x32(a0, a1, 0u, 0u, c0, c1);
  tf2x32(a0, a1, 0u, 1u, d0, d1);
  (void)c0; (void)c1;
  tf2x32(b0, b1, 0u, i, o0, o1);
#if RNG_VARIANT == 0
  v1 = o1;
#else
  v1 = o0;
#endif
  tf2x32(d0, d1, 0u, i, o0, o1);
#if RNG_VARIANT == 0
  v2 = o1;
#else
  v2 = o0;
#endif
#endif
  bits1[i] = v1;
  bits2[i] = v2;
  atomicAdd(&hist[v1 >> 20], 1);
  atomicAdd(&hist[4096 + (v2 >> 20)], 1);
}

__global__ void vq_hscan(const int* __restrict__ hist, int* __restrict__ base) {
  int s = blockIdx.x;           // sort 0/1
  int t = threadIdx.x;
  __shared__ int wsum[4];
  int p = 0;
  int loc[16];
#pragma unroll
  for (int c = 0; c < 16; c++) { loc[c] = hist[s * 4096 + t * 16 + c]; p += loc[c]; }
  int orig = p;
  int lane = t & 63, wave = t >> 6;
#pragma unroll
  for (int off = 1; off < 64; off <<= 1) {
    int v = __shfl_up(p, off, 64);
    if (lane >= off) p += v;
  }
  if (lane == 63) wsum[wave] = p;
  __syncthreads();
  int add = 0;
  for (int w = 0; w < 4; w++) if (w < wave) add += wsum[w];
  int excl = p + add - orig;
#pragma unroll
  for (int c = 0; c < 16; c++) {
    base[s * 4100 + t * 16 + c] = excl;
    excl += loc[c];
  }
  if (t == 255) base[s * 4100 + 4096] = excl;
}

__global__ void vq_scatter(const uint32_t* __restrict__ bits1, const uint32_t* __restrict__ bits2,
                           const int* __restrict__ base, int* __restrict__ cur,
                           int* __restrict__ slot) {
  int i = blockIdx.x * 256 + threadIdx.x;
  {
    int b = bits1[i] >> 20;
    int pos = atomicAdd(&cur[b], 1);
    slot[base[b] + pos] = i;
  }
  {
    int b = bits2[i] >> 20;
    int pos = atomicAdd(&cur[4096 + b], 1);
    slot[16384 + base[4100 + b] + pos] = i;
  }
}

__global__ void vq_rank2(const uint32_t* __restrict__ bits1, const uint32_t* __restrict__ bits2,
                         const int* __restrict__ base, const int* __restrict__ slot,
                         uint32_t* __restrict__ rank1, uint32_t* __restrict__ rank2) {
  int g = blockIdx.x * 256 + threadIdx.x;
  int s = g >> 14, i = g & 16383;
  const uint32_t* bits = s ? bits2 : bits1;
  uint32_t ki = bits[i];
  int b = ki >> 20;
  int lo = base[s * 4100 + b], hi = base[s * 4100 + b + 1];
  int cnt = lo;
  for (int e = lo; e < hi; e++) {
    int j = slot[s * 16384 + e];
    uint32_t kj = bits[j];
    cnt += (kj < ki) || (kj == ki && j < i);
  }
  if (s) rank2[i] = (uint32_t)cnt; else rank1[i] = (uint32_t)cnt;
}

__global__ void vq_krand(const uint32_t* __restrict__ rank1, const uint32_t* __restrict__ rank2,
                         int* __restrict__ krand) {
  int i = blockIdx.x * 256 + threadIdx.x;
  uint32_t j = rank1[i] & 16383u;
  uint32_t p = rank2[j];
  if (p < K_) krand[p] = i;
}

// ---------------- MFMA argmin: 128x128 tile, BK=64, split-bf16 3-term ----------------
// K-loop staging: round-5 layout (coalesced 128B rows + XOR chunk swizzle).
// Epilogue: [128][33]-padded reduce arrays (was [128][32] -> 64-lane same-bank).
__global__ __launch_bounds__(256, 2) void vq_argmin_mfma(
    const ushort_t* __restrict__ xhi, const ushort_t* __restrict__ xlo,
    const ushort_t* __restrict__ khi, const ushort_t* __restrict__ klo,
    const float* __restrict__ x2, const float* __restrict__ k2,
    unsigned long long* __restrict__ pm1, float* __restrict__ pm2) {
  __shared__ __align__(16) char smem[65536];
  int tid = threadIdx.x;
  int bx = blockIdx.x & 127, by = blockIdx.x >> 7;
  int row0 = bx * 128, col0 = by * 128;
  int lane = tid & 63, wid = tid >> 6;
  int wm = wid >> 1, wn = wid & 1;
  int lr = lane & 15, quad = lane >> 4;

  const char* gb[4];
  gb[0] = (const char*)xhi + (size_t)row0 * 1024;
  gb[1] = (const char*)xlo + (size_t)row0 * 1024;
  gb[2] = (const char*)khi + (size_t)col0 * 1024;
  gb[3] = (const char*)klo + (size_t)col0 * 1024;
  uint32_t goff[4], loff[4];
#pragma unroll
  for (int it = 0; it < 4; it++) {
    int cid = it * 256 + tid;
    int row = cid >> 3;
    int cc = (cid & 7) ^ (row & 7);
    goff[it] = row * 1024 + cc * 16;
    loff[it] = cid * 16;
  }
  uint32_t aoff[4], boff[4];
#pragma unroll
  for (int i = 0; i < 4; i++) {
    int ra = wm * 64 + i * 16 + lr;
    aoff[i] = ra * 128 + ((quad ^ (ra & 7)) * 16);
    int rb = wn * 64 + i * 16 + lr;
    boff[i] = rb * 128 + ((quad ^ (rb & 7)) * 16);
  }
  f32x4 acc[4][4] = {};

  for (int kt = 0; kt < 8; kt++) {
    uint32_t kofs = (uint32_t)kt * 128;
#pragma unroll
    for (int tl = 0; tl < 4; tl++)
#pragma unroll
      for (int it = 0; it < 4; it++)
        gload_lds16(gb[tl] + goff[it] + kofs, &smem[tl * 16384 + loff[it]]);
    __syncthreads();
#pragma unroll
    for (int kk = 0; kk < 2; kk++) {
      uint32_t kx = (uint32_t)kk << 6;
      short8 ah[4], al[4], bh[4], bl[4];
#pragma unroll
      for (int i = 0; i < 4; i++) {
        ah[i] = *(const short8*)&smem[(aoff[i] ^ kx)];
        al[i] = *(const short8*)&smem[16384 + (aoff[i] ^ kx)];
        bh[i] = *(const short8*)&smem[32768 + (boff[i] ^ kx)];
        bl[i] = *(const short8*)&smem[49152 + (boff[i] ^ kx)];
      }
#pragma unroll
      for (int i = 0; i < 4; i++)
#pragma unroll
        for (int j = 0; j < 4; j++) {
          acc[i][j] = __builtin_amdgcn_mfma_f32_16x16x32_bf16(ah[i], bh[j], acc[i][j], 0, 0, 0);
          acc[i][j] = __builtin_amdgcn_mfma_f32_16x16x32_bf16(ah[i], bl[j], acc[i][j], 0, 0, 0);
          acc[i][j] = __builtin_amdgcn_mfma_f32_16x16x32_bf16(al[i], bh[j], acc[i][j], 0, 0, 0);
        }
    }
    __syncthreads();
  }

  // epilogue: per-row top-2 into LDS [128][33] (padded), then 32-slot merge
  unsigned long long* L1 = (unsigned long long*)smem;   // [128][33] u64, 33792 B
  float* L2f = (float*)&smem[33792];                    // [128][33] f32, 16896 B
  float k2c[4];
#pragma unroll
  for (int j = 0; j < 4; j++) k2c[j] = k2[col0 + wn * 64 + j * 16 + lr];
#pragma unroll
  for (int i = 0; i < 4; i++) {
#pragma unroll
    for (int r = 0; r < 4; r++) {
      int row_l = wm * 64 + i * 16 + quad * 4 + r;
      float x2r = x2[row0 + row_l];
      float m1 = 3.4e38f, m2 = 3.4e38f; int mi = 0;
#pragma unroll
      for (int j = 0; j < 4; j++) {
        float d = (x2r - 2.0f * acc[i][j][r]) + k2c[j];
        int kg = col0 + wn * 64 + j * 16 + lr;
        if (d < m1) { m2 = m1; m1 = d; mi = kg; } else m2 = fminf(m2, d);
      }
      L1[row_l * 33 + wn * 16 + lr] =
          (((unsigned long long)__float_as_uint(m1)) << 32) | (unsigned)mi;
      L2f[row_l * 33 + wn * 16 + lr] = m2;
    }
  }
  __syncthreads();
  if (tid < 128) {
    unsigned long long b1 = L1[tid * 33];
    float b2 = L2f[tid * 33];
    for (int c = 1; c < 32; c++) {
      unsigned long long v = L1[tid * 33 + c];
      float vf = L2f[tid * 33 + c];
      if (v < b1) { b2 = fminf(b2, __uint_as_float((unsigned)(b1 >> 32))); b1 = v; }
      else b2 = fminf(b2, __uint_as_float((unsigned)(v >> 32)));
      b2 = fminf(b2, vf);
    }
    pm1[(size_t)by * NT_ + row0 + tid] = b1;
    pm2[(size_t)by * NT_ + row0 + tid] = b2;
  }
}

// ---------------- merge 16 col-blocks -> packed + compacted near-tie list ----------------
__global__ void vq_merge(const unsigned long long* __restrict__ pm1,
                         const float* __restrict__ pm2,
                         unsigned long long* __restrict__ packed,
                         int* __restrict__ flist, int* __restrict__ nflag) {
  int r = blockIdx.x * 256 + threadIdx.x;
  unsigned long long b1 = pm1[r];
  float b2 = pm2[r];
  for (int c = 1; c < 16; c++) {
    unsigned long long v = pm1[(size_t)c * NT_ + r];
    float vf = pm2[(size_t)c * NT_ + r];
    if (v < b1) { b2 = fminf(b2, __uint_as_float((unsigned)(b1 >> 32))); b1 = v; }
    else b2 = fminf(b2, __uint_as_float((unsigned)(v >> 32)));
    b2 = fminf(b2, vf);
  }
  if ((b2 - __uint_as_float((unsigned)(b1 >> 32))) < 3e-4f) {
    packed[r] = 0xFFFFFFFFFFFFFFFFull;
    int pos = atomicAdd(nflag, 1);
    flist[pos] = r;
  } else {
    packed[r] = b1;
  }
}

// ---------------- gather flagged x rows to dense fp32 (coalesced writes) ----------------
__global__ void vq_gatherx(const float* __restrict__ x, const int* __restrict__ flist,
                           const int* __restrict__ nflag, float* __restrict__ xg) {
  int nf = *nflag; if (nf > XG_CAP) nf = XG_CAP;
  int total = nf * 512;
  for (int e = blockIdx.x * 256 + threadIdx.x; e < total; e += gridDim.x * 256) {
    int ii = e >> 9, c = e & 511;
    int r = flist[ii];
    xg[e] = x[(size_t)(r >> 10) * 524288 + (size_t)c * 1024 + (r & 1023)];
  }
}

// ---------------- fp32 exact repair: (8-row group) x (256-cluster chunk) ----------------
__global__ void vq_repair(const float* __restrict__ x, const float* __restrict__ k,
                          const float* __restrict__ xg,
                          const float* __restrict__ x2, const float* __restrict__ k2,
                          const int* __restrict__ flist, const int* __restrict__ nflag,
                          unsigned long long* __restrict__ packed) {
  __shared__ float xs[8][512];
  __shared__ unsigned long long part[8][4];
  int tid = threadIdx.x;
  int lane = tid & 63, wave = tid >> 6;
  int nf = *nflag;
  int ngrp = (nf + 7) >> 3;
  int nwork = ngrp * 8;
  for (int wi = blockIdx.x; wi < nwork; wi += gridDim.x) {
    int g = wi >> 3, c = wi & 7;
    int base = g * 8;
    for (int e = tid; e < 8 * 512; e += 256) {
      int rr = e >> 9, cc = e & 511;
      int ii = base + rr;
      float v = 0.f;
      if (ii < nf) {
        if (ii < XG_CAP) v = xg[ii * 512 + cc];
        else { int r = flist[ii]; v = x[(size_t)(r >> 10) * 524288 + (size_t)cc * 1024 + (r & 1023)]; }
      }
      xs[rr][cc] = v;
    }
    __syncthreads();
    int j = c * 256 + tid;
    const float4* kr = (const float4*)(k + (size_t)j * 512);
    float dot[8] = {0.f, 0.f, 0.f, 0.f, 0.f, 0.f, 0.f, 0.f};
    for (int w4 = 0; w4 < 128; w4++) {
      float4 kv = kr[w4];
#pragma unroll
      for (int rr = 0; rr < 8; rr++) {
        const float4 xv = *(const float4*)&xs[rr][w4 * 4];
        dot[rr] = fmaf(xv.x, kv.x, dot[rr]);
        dot[rr] = fmaf(xv.y, kv.y, dot[rr]);
        dot[rr] = fmaf(xv.z, kv.z, dot[rr]);
        dot[rr] = fmaf(xv.w, kv.w, dot[rr]);
      }
    }
    float k2j = k2[j];
#pragma unroll
    for (int rr = 0; rr < 8; rr++) {
      int ii = base + rr;
      unsigned long long pv = 0xFFFFFFFFFFFFFFFFull;
      if (ii < nf) {
        int r = flist[ii];
        float d = (x2[r] - 2.0f * dot[rr]) + k2j;
        pv = (((unsigned long long)__float_as_uint(d)) << 32) | (unsigned)j;
      }
      for (int off = 32; off; off >>= 1) {
        unsigned long long o = __shfl_down(pv, off, 64);
        if (o < pv) pv = o;
      }
      if (lane == 0) part[rr][wave] = pv;
    }
    __syncthreads();
    if (tid < 8) {
      int ii = base + tid;
      if (ii < nf) {
        unsigned long long m = part[tid][0];
        if (part[tid][1] < m) m = part[tid][1];
        if (part[tid][2] < m) m = part[tid][2];
        if (part[tid][3] < m) m = part[tid][3];
        atomicMin(&packed[flist[ii]], m);
      }
    }
    __syncthreads();
  }
}

// ---------------- x_l, counts, fit ----------------
__global__ void vq_cnt2(const unsigned long long* __restrict__ packed,
                        float* __restrict__ counts, float* __restrict__ scal,
                        float* __restrict__ out) {
  int tid = threadIdx.x;
  int r = blockIdx.x * 256 + tid;
  unsigned long long p = packed[r];
  unsigned idx = (unsigned)(p & 0xFFFFFFFFull);
  float md = __uint_as_float((unsigned)(p >> 32));
  out[O_XL + r] = (float)idx;
  atomicAdd(&counts[idx], 1.0f);
  float s = md;
  for (int off = 32; off; off >>= 1) s += __shfl_down(s, off, 64);
  __shared__ float rs[4];
  if ((tid & 63) == 0) rs[tid >> 6] = s;
  __syncthreads();
  if (tid == 0) atomicAdd(&scal[2], rs[0] + rs[1] + rs[2] + rs[3]);
}

// ---------------- exclusive scan of counts -> offsets ----------------
__global__ void vq_scan(const float* __restrict__ counts, int* __restrict__ offs) {
  __shared__ int ls[256];
  int t = threadIdx.x;
  int s = 0;
#pragma unroll
  for (int c = 0; c < 8; c++) s += (int)counts[t * 8 + c];
  ls[t] = s;
  __syncthreads();
  if (t == 0) {
    int run = 0;
    for (int i = 0; i < 256; i++) { int v = ls[i]; ls[i] = run; run += v; }
  }
  __syncthreads();
  int base = ls[t];
#pragma unroll
  for (int c = 0; c < 8; c++) {
    offs[t * 8 + c] = base;
    base += (int)counts[t * 8 + c];
  }
  if (t == 255) offs[2048] = base;
}

// ---------------- fill CSR row list ----------------
__global__ void vq_fill(const unsigned long long* __restrict__ packed,
                        const int* __restrict__ offs, int* __restrict__ cursor,
                        int* __restrict__ rowl) {
  int r = blockIdx.x * 256 + threadIdx.x;
  int idx = (int)(packed[r] & 0xFFFFFFFFull);
  int pos = atomicAdd(&cursor[idx], 1);
  rowl[offs[idx] + pos] = r;
}

// ---------------- x_d gather/store ----------------
__global__ void vq_xd(const float* __restrict__ k,
                      const unsigned long long* __restrict__ packed,
                      float* __restrict__ out) {
  __shared__ float kb[16][513];
  __shared__ int lrow[16];
  int rb = blockIdx.x;
  int row0 = rb * 16;
  int n = row0 >> 10, t0 = row0 & 1023;
  int tid = threadIdx.x;
  if (tid < 16) lrow[tid] = (int)(packed[row0 + tid] & 0xFFFFFFFFull);
  __syncthreads();
  for (int i = tid; i < 16 * 512; i += 256) {
    int rr = i >> 9, c = i & 511;
    kb[rr][c] = k[(size_t)lrow[rr] * 512 + c];
  }
  __syncthreads();
  int tp = tid & 15, wp = tid >> 4;
  float* xd = out + O_XD;
  int t = t0 + tp;
#pragma unroll 4
  for (int wi = 0; wi < 32; wi++) {
    int w = wi * 16 + wp;
    xd[(size_t)n * 524288 + (size_t)w * 1024 + t] = kb[tp][w];
  }
}

// ---------------- codebook EMA update via CSR gather ----------------
__global__ void vq_knew_csr(const ushort_t* __restrict__ xhi, const ushort_t* __restrict__ xlo,
                            const float* __restrict__ k, const float* __restrict__ ksum_in,
                            const float* __restrict__ kelem_in, const int* __restrict__ offs,
                            const int* __restrict__ rowl, const int* __restrict__ krand,
                            float* __restrict__ out, float* __restrict__ scal) {
  int j = blockIdx.x, tid = threadIdx.x;
  int o0 = offs[j], o1 = offs[j + 1];
  float s0 = 0.f, s1 = 0.f;
  for (int p = o0; p < o1; p++) {
    int r = rowl[p];
    const ushort_t* hp = &xhi[(size_t)r * 512];
    const ushort_t* lp = &xlo[(size_t)r * 512];
    s0 += bf2f(hp[tid]) + bf2f(lp[tid]);
    s1 += bf2f(hp[tid + 256]) + bf2f(lp[tid + 256]);
  }
  float cnt = (float)(o1 - o0);
  float ken = 0.99f * kelem_in[j] + 0.01f * cnt;
  bool use = (ken >= 1.0f);
  int ir = krand[j] & 16383;
  float dd = 0.f;
  {
    float ksn = 0.99f * ksum_in[(size_t)j * 512 + tid] + 0.01f * s0;
    out[O_KSN + (size_t)j * 512 + tid] = ksn;
    float kn = use ? (ksn / ken)
                   : (bf2f(xhi[(size_t)ir * 512 + tid]) + bf2f(xlo[(size_t)ir * 512 + tid]));
    out[O_KNEW + (size_t)j * 512 + tid] = kn;
    float d = kn - k[(size_t)j * 512 + tid];
    dd += d * d;
  }
  {
    int w = tid + 256;
    float ksn = 0.99f * ksum_in[(size_t)j * 512 + w] + 0.01f * s1;
    out[O_KSN + (size_t)j * 512 + w] = ksn;
    float kn = use ? (ksn / ken)
                   : (bf2f(xhi[(size_t)ir * 512 + w]) + bf2f(xlo[(size_t)ir * 512 + w]));
    out[O_KNEW + (size_t)j * 512 + w] = kn;
    float d = kn - k[(size_t)j * 512 + w];
    dd += d * d;
  }
  for (int off = 32; off; off >>= 1) dd += __shfl_down(dd, off, 64);
  __shared__ float r4[4];
  if ((tid & 63) == 0) r4[tid >> 6] = dd;
  __syncthreads();
  if (tid == 0) {
    atomicAdd(&scal[3], r4[0] + r4[1] + r4[2] + r4[3]);
    out[O_KEN + j] = ken;
  }
}

// ---------------- scalars ----------------
__global__ void vq_fin(const float* __restrict__ counts, const float* __restrict__ scal,
                       float* __restrict__ out) {
  int tid = threadIdx.x;
  float e = 0.f;
  for (int j = tid; j < K_; j += 256) {
    float p = counts[j] * (1.0f / 16384.0f);
    e -= p * logf(p + 1e-8f);
  }
  for (int off = 32; off; off >>= 1) e += __shfl_down(e, off, 64);
  __shared__ float r[4];
  if ((tid & 63) == 0) r[tid >> 6] = e;
  __syncthreads();
  if (tid == 0) {
    float ent = r[0] + r[1] + r[2] + r[3];
    float sum = scal[0], sumsq = scal[1], fits = scal[2], d2 = scal[3];
    const float S = 8388608.f;
    out[O_SC + 0] = fits / S;
    out[O_SC + 1] = fits / 16384.f;
    out[O_SC + 2] = sqrtf((sumsq - sum * sum / S) / S);
    out[O_SC + 3] = ent;
    out[O_SC + 4] = sqrtf(d2 / 1048576.f);
  }
}

extern "C" void kernel_launch(void* const* d_in, const int* in_sizes, int n_in,
                              void* d_out, int out_size, void* d_ws, size_t ws_size,
                              hipStream_t stream) {
  (void)in_sizes; (void)n_in; (void)out_size; (void)ws_size;
  const float* x        = (const float*)d_in[0];
  const float* k        = (const float*)d_in[1];
  const float* ksum_in  = (const float*)d_in[2];
  const float* kelem_in = (const float*)d_in[3];
  float* out = (float*)d_out;
  uint8_t* ws = (uint8_t*)d_ws;

  ushort_t* xhi = (ushort_t*)(ws + OFF_XHI);
  ushort_t* xlo = (ushort_t*)(ws + OFF_XLO);
  ushort_t* khi = (ushort_t*)(ws + OFF_KHI);
  ushort_t* klo = (ushort_t*)(ws + OFF_KLO);
  unsigned long long* pm1 = (unsigned long long*)(ws + OFF_PM1);
  float*    pm2    = (float*)(ws + OFF_PM2);
  float*    xg     = (float*)(ws + OFF_XG);
  int*      rhist  = (int*)(ws + R_HIST);
  int*      rcur   = (int*)(ws + R_CUR);
  int*      rbase  = (int*)(ws + R_BASE);
  int*      rslot  = (int*)(ws + R_SLOT);
  unsigned long long* packed = (unsigned long long*)(ws + OFF_PACKED);
  int*      flist  = (int*)(ws + OFF_FLIST);
  float*    x2v    = (float*)(ws + OFF_X2);
  float*    k2v    = (float*)(ws + OFF_K2);
  float*    scal   = (float*)(ws + OFF_SCAL);
  int*      nflag  = (int*)(ws + OFF_SCAL + 32);
  float*    counts = (float*)(ws + OFF_COUNTS);
  int*      cursor = (int*)(ws + OFF_CURSOR);
  uint32_t* rank1  = (uint32_t*)(ws + OFF_RANK1);
  uint32_t* rank2  = (uint32_t*)(ws + OFF_RANK2);
  uint32_t* bits1  = (uint32_t*)(ws + OFF_BITS1);
  uint32_t* bits2  = (uint32_t*)(ws + OFF_BITS2);
  int*      offs   = (int*)(ws + OFF_OFFS);
  int*      rowl   = (int*)(ws + OFF_ROWL);
  int*      krand  = (int*)(ws + OFF_KRAND);

  hipMemsetAsync(ws + OFF_SCAL, 0, ZERO_LEN, stream);
  hipMemsetAsync(ws + R_HIST, 0, 65536, stream);   // hist + cursor

  vq_prep_x<<<256, 256, 0, stream>>>(x, xhi, xlo, x2v, scal);
  vq_prep_k<<<256, 256, 0, stream>>>(k, khi, klo, k2v);
  vq_bits<<<64, 256, 0, stream>>>(bits1, bits2, rhist);
  vq_hscan<<<2, 256, 0, stream>>>(rhist, rbase);
  vq_scatter<<<64, 256, 0, stream>>>(bits1, bits2, rbase, rcur, rslot);
  vq_rank2<<<128, 256, 0, stream>>>(bits1, bits2, rbase, rslot, rank1, rank2);
  vq_krand<<<64, 256, 0, stream>>>(rank1, rank2, krand);
  vq_argmin_mfma<<<2048, 256, 0, stream>>>(xhi, xlo, khi, klo, x2v, k2v, pm1, pm2);
  vq_merge<<<64, 256, 0, stream>>>(pm1, pm2, packed, flist, nflag);
  vq_gatherx<<<256, 256, 0, stream>>>(x, flist, nflag, xg);
  vq_repair<<<512, 256, 0, stream>>>(x, k, xg, x2v, k2v, flist, nflag, packed);
  vq_cnt2<<<64, 256, 0, stream>>>(packed, counts, scal, out);
  vq_scan<<<1, 256, 0, stream>>>(counts, offs);
  vq_fill<<<64, 256, 0, stream>>>(packed, offs, cursor, rowl);
  vq_xd<<<1024, 256, 0, stream>>>(k, packed, out);
  vq_knew_csr<<<2048, 256, 0, stream>>>(xhi, xlo, k, ksum_in, kelem_in, offs, rowl, krand, out, scal);
  vq_fin<<<1, 256, 0, stream>>>(counts, scal, out);
}